// Round 1
// baseline (7567.250 us; speedup 1.0000x reference)
//
#include <hip/hip_runtime.h>

#define NN 100000
#define NE 1600000
#define HD 128
#define HD2 256

static inline int cdiv(int a, int b){ return (a + b - 1) / b; }

// ---------------- utility kernels ----------------
__global__ void k_zero_int(int* __restrict__ p, int n){
  int i = blockIdx.x * 256 + threadIdx.x;
  if(i < n) p[i] = 0;
}

__global__ void k_zero_f2(float* __restrict__ a, float* __restrict__ b, int n){
  int i = blockIdx.x * 256 + threadIdx.x;
  if(i < n){ a[i] = 0.f; b[i] = 0.f; }
}

__global__ void k_hist(const int* __restrict__ rows, int* __restrict__ cnt){
  int e = blockIdx.x * 256 + threadIdx.x;
  if(e < NE) atomicAdd(&cnt[rows[e]], 1);
}

// scan1: each block scans 1024 elements (256 thr x 4), writes partial scan + block sum
__global__ void k_scan1(const int* __restrict__ cnt, int* __restrict__ part,
                        int* __restrict__ sums, int n){
  __shared__ int sh[256];
  int tid = threadIdx.x;
  int base = blockIdx.x * 1024 + tid * 4;
  int v0 = (base + 0 < n) ? cnt[base + 0] : 0;
  int v1 = (base + 1 < n) ? cnt[base + 1] : 0;
  int v2 = (base + 2 < n) ? cnt[base + 2] : 0;
  int v3 = (base + 3 < n) ? cnt[base + 3] : 0;
  int s = v0 + v1 + v2 + v3;
  sh[tid] = s;
  __syncthreads();
  for(int d = 1; d < 256; d <<= 1){
    int t = (tid >= d) ? sh[tid - d] : 0;
    __syncthreads();
    sh[tid] += t;
    __syncthreads();
  }
  int excl = sh[tid] - s;
  if(tid == 255) sums[blockIdx.x] = sh[255];
  if(base + 0 < n) part[base + 0] = excl;
  if(base + 1 < n) part[base + 1] = excl + v0;
  if(base + 2 < n) part[base + 2] = excl + v0 + v1;
  if(base + 3 < n) part[base + 3] = excl + v0 + v1 + v2;
}

__global__ void k_scan2(int* __restrict__ sums, int nb){
  __shared__ int sh[128];
  int tid = threadIdx.x;
  int v = (tid < nb) ? sums[tid] : 0;
  sh[tid] = v;
  __syncthreads();
  for(int d = 1; d < 128; d <<= 1){
    int t = (tid >= d) ? sh[tid - d] : 0;
    __syncthreads();
    sh[tid] += t;
    __syncthreads();
  }
  if(tid < nb) sums[tid] = sh[tid] - v;   // exclusive
}

__global__ void k_scan3(int* __restrict__ rowptr, int* __restrict__ cursor,
                        const int* __restrict__ sums, int n){
  int tid = threadIdx.x;
  int off = sums[blockIdx.x];
  int base = blockIdx.x * 1024 + tid * 4;
  #pragma unroll
  for(int j = 0; j < 4; j++){
    int idx = base + j;
    if(idx < n){ int r = rowptr[idx] + off; rowptr[idx] = r; cursor[idx] = r; }
  }
  if(blockIdx.x == 0 && tid == 0) rowptr[n] = NE;
}

__global__ void k_scatter(const int* __restrict__ rows, const int* __restrict__ cols,
                          const float* __restrict__ vals, int* __restrict__ cursor,
                          int* __restrict__ ocol, float* __restrict__ oval){
  int e = blockIdx.x * 256 + threadIdx.x;
  if(e < NE){
    int r = rows[e];
    int pp = atomicAdd(&cursor[r], 1);
    ocol[pp] = cols[e];
    oval[pp] = vals[e];
  }
}

// ---------------- SpMM: one wave per node, relu (+ optional l2norm) fused ----------------
template<bool NORM>
__global__ void k_spmm(const int* __restrict__ rowptr, const int* __restrict__ col,
                       const float* __restrict__ val, const float* __restrict__ X,
                       float* __restrict__ out){
  int node = (blockIdx.x << 2) + (threadIdx.x >> 6);
  int lane = threadIdx.x & 63;
  if(node >= NN) return;
  int s = rowptr[node], e = rowptr[node + 1];
  float ax = 0.f, ay = 0.f;
  int i = s;
  for(; i + 1 < e; i += 2){
    int   c0 = col[i],   c1 = col[i + 1];
    float v0 = val[i],   v1 = val[i + 1];
    float2 x0 = *(const float2*)(X + (size_t)c0 * HD + lane * 2);
    float2 x1 = *(const float2*)(X + (size_t)c1 * HD + lane * 2);
    ax += v0 * x0.x + v1 * x1.x;
    ay += v0 * x0.y + v1 * x1.y;
  }
  if(i < e){
    int c = col[i]; float v = val[i];
    float2 xv = *(const float2*)(X + (size_t)c * HD + lane * 2);
    ax += v * xv.x; ay += v * xv.y;
  }
  ax = fmaxf(ax, 0.f);
  ay = fmaxf(ay, 0.f);
  if(NORM){
    float ss = ax * ax + ay * ay;
    #pragma unroll
    for(int o = 32; o >= 1; o >>= 1) ss += __shfl_xor(ss, o, 64);
    float scale = 1.f / fmaxf(sqrtf(ss), 1e-12f);
    ax *= scale; ay *= scale;
  }
  *(float2*)(out + (size_t)node * HD + lane * 2) = make_float2(ax, ay);
}

// ---------------- fp32 SGEMM: 128x128 tile, 8x8 micro, 256 threads ----------------
// BIASRELU: C = relu(A@B + bias). FUSE: also score[m] += sum_n C[m,n]*m3[n] (no C store).
template<bool BIASRELU, bool FUSE>
__launch_bounds__(256)
__global__ void k_gemm(const float* __restrict__ A, const float* __restrict__ B,
                       const float* __restrict__ bias, float* __restrict__ C,
                       const float* __restrict__ m3, float* __restrict__ score,
                       int M, int K, int Ncol){
  __shared__ float a_s[16][132];
  __shared__ float b_s[16][136];
  int tid = threadIdx.x;
  int tx = tid & 15, ty = tid >> 4;
  int m0 = blockIdx.x * 128;
  int n0 = blockIdx.y * 128;

  float acc[8][8];
  #pragma unroll
  for(int i = 0; i < 8; i++)
    #pragma unroll
    for(int j = 0; j < 8; j++) acc[i][j] = 0.f;

  int am = tid >> 1;            // 0..127 (row within tile)
  int ak = (tid & 1) * 8;       // 0 or 8 (k offset)
  int arow = m0 + am; if(arow >= M) arow = M - 1;   // clamp tail rows
  const float* Arow = A + (size_t)arow * K;
  int bk = tid >> 4;            // 0..15
  int bn = (tid & 15) * 8;      // 0..120

  for(int k0 = 0; k0 < K; k0 += 16){
    float4 av0 = *(const float4*)(Arow + k0 + ak);
    float4 av1 = *(const float4*)(Arow + k0 + ak + 4);
    float4 bv0 = *(const float4*)(B + (size_t)(k0 + bk) * Ncol + n0 + bn);
    float4 bv1 = *(const float4*)(B + (size_t)(k0 + bk) * Ncol + n0 + bn + 4);
    if(k0) __syncthreads();
    a_s[ak + 0][am] = av0.x; a_s[ak + 1][am] = av0.y;
    a_s[ak + 2][am] = av0.z; a_s[ak + 3][am] = av0.w;
    a_s[ak + 4][am] = av1.x; a_s[ak + 5][am] = av1.y;
    a_s[ak + 6][am] = av1.z; a_s[ak + 7][am] = av1.w;
    *(float4*)&b_s[bk][bn]     = bv0;
    *(float4*)&b_s[bk][bn + 4] = bv1;
    __syncthreads();
    #pragma unroll
    for(int k = 0; k < 16; k++){
      float a[8], b[8];
      *(float4*)&a[0] = *(const float4*)&a_s[k][ty * 8];
      *(float4*)&a[4] = *(const float4*)&a_s[k][ty * 8 + 4];
      *(float4*)&b[0] = *(const float4*)&b_s[k][tx * 8];
      *(float4*)&b[4] = *(const float4*)&b_s[k][tx * 8 + 4];
      #pragma unroll
      for(int i = 0; i < 8; i++)
        #pragma unroll
        for(int j = 0; j < 8; j++)
          acc[i][j] = fmaf(a[i], b[j], acc[i][j]);
    }
  }

  int nbase = n0 + tx * 8;
  if(BIASRELU){
    float bv[8];
    *(float4*)&bv[0] = *(const float4*)(bias + nbase);
    *(float4*)&bv[4] = *(const float4*)(bias + nbase + 4);
    #pragma unroll
    for(int i = 0; i < 8; i++)
      #pragma unroll
      for(int j = 0; j < 8; j++)
        acc[i][j] = fmaxf(acc[i][j] + bv[j], 0.f);
  }

  if(FUSE){
    float w3[8];
    *(float4*)&w3[0] = *(const float4*)(m3 + nbase);
    *(float4*)&w3[4] = *(const float4*)(m3 + nbase + 4);
    float part[8];
    #pragma unroll
    for(int i = 0; i < 8; i++){
      float ps = 0.f;
      #pragma unroll
      for(int j = 0; j < 8; j++) ps = fmaf(acc[i][j], w3[j], ps);
      part[i] = ps;
    }
    __syncthreads();
    float* red = &a_s[0][0];   // reuse LDS: need 128*16 = 2048 floats (a_s has 2112)
    #pragma unroll
    for(int i = 0; i < 8; i++) red[(ty * 8 + i) * 16 + tx] = part[i];
    __syncthreads();
    if(tid < 128){
      float ssum = 0.f;
      #pragma unroll
      for(int t = 0; t < 16; t++) ssum += red[tid * 16 + t];
      int m = m0 + tid;
      if(m < M) atomicAdd(&score[m], ssum);
    }
  } else {
    #pragma unroll
    for(int i = 0; i < 8; i++){
      int m = m0 + ty * 8 + i;
      if(m < M){
        float* Cr = C + (size_t)m * Ncol + nbase;
        *(float4*)Cr       = make_float4(acc[i][0], acc[i][1], acc[i][2], acc[i][3]);
        *(float4*)(Cr + 4) = make_float4(acc[i][4], acc[i][5], acc[i][6], acc[i][7]);
      }
    }
  }
}

__global__ void k_final(const float* __restrict__ s1, const float* __restrict__ s2,
                        const float* __restrict__ b3, float* __restrict__ out){
  int i = blockIdx.x * 256 + threadIdx.x;
  if(i < NN){
    float b = 9.f * b3[0];
    out[i] = (s1[i] + b) * (s2[i] + b);
  }
}

// ---------------- launcher ----------------
extern "C" void kernel_launch(void* const* d_in, const int* in_sizes, int n_in,
                              void* d_out, int out_size, void* d_ws, size_t ws_size,
                              hipStream_t stream){
  const int*   a1r = (const int*)d_in[0];
  const int*   a1c = (const int*)d_in[1];
  const float* a1v = (const float*)d_in[2];
  const int*   a2r = (const int*)d_in[3];
  const int*   a2c = (const int*)d_in[4];
  const float* a2v = (const float*)d_in[5];
  const float* w1  = (const float*)d_in[6];
  const float* w[8];
  for(int i = 0; i < 8; i++) w[i] = (const float*)d_in[7 + i];
  const float* m1 = (const float*)d_in[15];
  const float* b1 = (const float*)d_in[16];
  const float* m2 = (const float*)d_in[17];
  const float* b2 = (const float*)d_in[18];
  const float* m3 = (const float*)d_in[19];
  const float* b3 = (const float*)d_in[20];
  float* out = (float*)d_out;

  // workspace layout (~182 MB)
  char* base = (char*)d_ws;
  size_t off = 0;
  auto alloc = [&](size_t bytes) -> char* {
    char* r = base + off;
    off += (bytes + 255) & ~(size_t)255;
    return r;
  };
  int*   c1ptr = (int*)  alloc((size_t)(NN + 1) * 4);
  int*   c1col = (int*)  alloc((size_t)NE * 4);
  float* c1val = (float*)alloc((size_t)NE * 4);
  int*   c2ptr = (int*)  alloc((size_t)(NN + 1) * 4);
  int*   c2col = (int*)  alloc((size_t)NE * 4);
  float* c2val = (float*)alloc((size_t)NE * 4);
  int*   cursor= (int*)  alloc((size_t)NN * 4);
  int*   sums  = (int*)  alloc(512);
  float* x     = (float*)alloc((size_t)NN * HD * 4);
  float* yh    = (float*)alloc((size_t)NN * HD2 * 4);  // y (N x 128) aliases h1 (N x 256)
  float* sc1   = (float*)alloc((size_t)NN * 4);
  float* sc2   = (float*)alloc((size_t)NN * 4);
  float* y  = yh;
  float* h1 = yh;

  const int SCAN_BLOCKS = cdiv(NN, 1024);   // 98
  auto build_csr = [&](const int* rows, const int* cols, const float* vals,
                       int* rptr, int* rcol, float* rval){
    hipLaunchKernelGGL(k_zero_int, dim3(cdiv(NN, 256)), dim3(256), 0, stream, cursor, NN);
    hipLaunchKernelGGL(k_hist,     dim3(cdiv(NE, 256)), dim3(256), 0, stream, rows, cursor);
    hipLaunchKernelGGL(k_scan1,    dim3(SCAN_BLOCKS),   dim3(256), 0, stream, cursor, rptr, sums, NN);
    hipLaunchKernelGGL(k_scan2,    dim3(1),             dim3(128), 0, stream, sums, SCAN_BLOCKS);
    hipLaunchKernelGGL(k_scan3,    dim3(SCAN_BLOCKS),   dim3(256), 0, stream, rptr, cursor, sums, NN);
    hipLaunchKernelGGL(k_scatter,  dim3(cdiv(NE, 256)), dim3(256), 0, stream, rows, cols, vals, cursor, rcol, rval);
  };

  const int GX = cdiv(NN, 128);   // 782
  auto mlp = [&](const float* xin, float* score){
    hipLaunchKernelGGL((k_gemm<true, false>), dim3(GX, 2), dim3(256), 0, stream,
                       xin, m1, b1, h1, (const float*)nullptr, (float*)nullptr, NN, HD, HD2);
    hipLaunchKernelGGL((k_gemm<true, true>),  dim3(GX, 2), dim3(256), 0, stream,
                       h1, m2, b2, (float*)nullptr, m3, score, NN, HD2, HD2);
  };

  auto branch = [&](const int* rptr, const int* rcol, const float* rval, float* score){
    hipLaunchKernelGGL((k_spmm<true>), dim3(cdiv(NN, 4)), dim3(256), 0, stream,
                       rptr, rcol, rval, w1, x);
    mlp(x, score);
    for(int i = 0; i < 8; i++){
      hipLaunchKernelGGL((k_gemm<false, false>), dim3(GX, 1), dim3(256), 0, stream,
                         x, w[i], (const float*)nullptr, y,
                         (const float*)nullptr, (float*)nullptr, NN, HD, HD);
      if(i < 7)
        hipLaunchKernelGGL((k_spmm<true>),  dim3(cdiv(NN, 4)), dim3(256), 0, stream,
                           rptr, rcol, rval, y, x);
      else
        hipLaunchKernelGGL((k_spmm<false>), dim3(cdiv(NN, 4)), dim3(256), 0, stream,
                           rptr, rcol, rval, y, x);
      mlp(x, score);
    }
  };

  build_csr(a1r, a1c, a1v, c1ptr, c1col, c1val);
  build_csr(a2r, a2c, a2v, c2ptr, c2col, c2val);
  hipLaunchKernelGGL(k_zero_f2, dim3(cdiv(NN, 256)), dim3(256), 0, stream, sc1, sc2, NN);
  branch(c1ptr, c1col, c1val, sc1);
  branch(c2ptr, c2col, c2val, sc2);
  hipLaunchKernelGGL(k_final, dim3(cdiv(NN, 256)), dim3(256), 0, stream, sc1, sc2, b3, out);
}

// Round 2
// 5028.141 us; speedup vs baseline: 1.5050x; 1.5050x over previous
//
#include <hip/hip_runtime.h>
#include <hip/hip_fp16.h>

#define NN 100000
#define NE 1600000
#define HD 128
#define HD2 256

typedef unsigned int u32;
typedef _Float16 half8 __attribute__((ext_vector_type(8)));
typedef float floatx4 __attribute__((ext_vector_type(4)));

static inline int cdiv(int a, int b){ return (a + b - 1) / b; }

// ---- split-fp16 packing: x ~= h + l * 2^-12, l pre-scaled by 4096 ----
__device__ __forceinline__ u32 split_pack(float v){
  __half h;
  if(fabsf(v) < 6.103515625e-05f) h = __ushort_as_half((unsigned short)0);
  else h = __float2half_rn(v);
  float hf = __half2float(h);
  __half l = __float2half_rn((v - hf) * 4096.0f);
  return (u32)__half_as_ushort(h) | ((u32)__half_as_ushort(l) << 16);
}

// ---------------- utility kernels ----------------
__global__ void k_zero_int(int* __restrict__ p, int n){
  int i = blockIdx.x * 256 + threadIdx.x;
  if(i < n) p[i] = 0;
}

__global__ void k_zero_f2(float* __restrict__ a, float* __restrict__ b, int n){
  int i = blockIdx.x * 256 + threadIdx.x;
  if(i < n){ a[i] = 0.f; b[i] = 0.f; }
}

__global__ void k_hist(const int* __restrict__ rows, int* __restrict__ cnt){
  int e = blockIdx.x * 256 + threadIdx.x;
  if(e < NE) atomicAdd(&cnt[rows[e]], 1);
}

__global__ void k_scan1(const int* __restrict__ cnt, int* __restrict__ part,
                        int* __restrict__ sums, int n){
  __shared__ int sh[256];
  int tid = threadIdx.x;
  int base = blockIdx.x * 1024 + tid * 4;
  int v0 = (base + 0 < n) ? cnt[base + 0] : 0;
  int v1 = (base + 1 < n) ? cnt[base + 1] : 0;
  int v2 = (base + 2 < n) ? cnt[base + 2] : 0;
  int v3 = (base + 3 < n) ? cnt[base + 3] : 0;
  int s = v0 + v1 + v2 + v3;
  sh[tid] = s;
  __syncthreads();
  for(int d = 1; d < 256; d <<= 1){
    int t = (tid >= d) ? sh[tid - d] : 0;
    __syncthreads();
    sh[tid] += t;
    __syncthreads();
  }
  int excl = sh[tid] - s;
  if(tid == 255) sums[blockIdx.x] = sh[255];
  if(base + 0 < n) part[base + 0] = excl;
  if(base + 1 < n) part[base + 1] = excl + v0;
  if(base + 2 < n) part[base + 2] = excl + v0 + v1;
  if(base + 3 < n) part[base + 3] = excl + v0 + v1 + v2;
}

__global__ void k_scan2(int* __restrict__ sums, int nb){
  __shared__ int sh[128];
  int tid = threadIdx.x;
  int v = (tid < nb) ? sums[tid] : 0;
  sh[tid] = v;
  __syncthreads();
  for(int d = 1; d < 128; d <<= 1){
    int t = (tid >= d) ? sh[tid - d] : 0;
    __syncthreads();
    sh[tid] += t;
    __syncthreads();
  }
  if(tid < nb) sums[tid] = sh[tid] - v;
}

__global__ void k_scan3(int* __restrict__ rowptr, int* __restrict__ cursor,
                        const int* __restrict__ sums, int n){
  int tid = threadIdx.x;
  int off = sums[blockIdx.x];
  int base = blockIdx.x * 1024 + tid * 4;
  #pragma unroll
  for(int j = 0; j < 4; j++){
    int idx = base + j;
    if(idx < n){ int r = rowptr[idx] + off; rowptr[idx] = r; cursor[idx] = r; }
  }
  if(blockIdx.x == 0 && tid == 0) rowptr[n] = NE;
}

__global__ void k_scatter(const int* __restrict__ rows, const int* __restrict__ cols,
                          const float* __restrict__ vals, int* __restrict__ cursor,
                          int* __restrict__ ocol, float* __restrict__ oval){
  int e = blockIdx.x * 256 + threadIdx.x;
  if(e < NE){
    int r = rows[e];
    int pp = atomicAdd(&cursor[r], 1);
    ocol[pp] = cols[e];
    oval[pp] = vals[e];
  }
}

// weight pre-split: W is [K][N] row-major fp32; out is packed [N][K] (transposed)
__global__ void k_splitw(const float* __restrict__ W, u32* __restrict__ out,
                         int K, int N, int total){
  int idx = blockIdx.x * 256 + threadIdx.x;
  if(idx < total){
    int n = idx / K, k = idx - n * K;
    out[idx] = split_pack(W[(size_t)k * N + n]);
  }
}

// ---------------- SpMM: one wave per node; relu (+ optional l2norm); packed-split output ----
template<bool NORM>
__global__ void k_spmm(const int* __restrict__ rowptr, const int* __restrict__ col,
                       const float* __restrict__ val, const float* __restrict__ X,
                       u32* __restrict__ outpk){
  int node = (blockIdx.x << 2) + (threadIdx.x >> 6);
  int lane = threadIdx.x & 63;
  if(node >= NN) return;
  int s = rowptr[node], e = rowptr[node + 1];
  float ax = 0.f, ay = 0.f;
  int i = s;
  for(; i + 1 < e; i += 2){
    int   c0 = col[i],   c1 = col[i + 1];
    float v0 = val[i],   v1 = val[i + 1];
    float2 x0 = *(const float2*)(X + (size_t)c0 * HD + lane * 2);
    float2 x1 = *(const float2*)(X + (size_t)c1 * HD + lane * 2);
    ax += v0 * x0.x + v1 * x1.x;
    ay += v0 * x0.y + v1 * x1.y;
  }
  if(i < e){
    int c = col[i]; float v = val[i];
    float2 xv = *(const float2*)(X + (size_t)c * HD + lane * 2);
    ax += v * xv.x; ay += v * xv.y;
  }
  ax = fmaxf(ax, 0.f);
  ay = fmaxf(ay, 0.f);
  if(NORM){
    float ss = ax * ax + ay * ay;
    #pragma unroll
    for(int o = 32; o >= 1; o >>= 1) ss += __shfl_xor(ss, o, 64);
    float scale = 1.f / fmaxf(sqrtf(ss), 1e-12f);
    ax *= scale; ay *= scale;
  }
  *(uint2*)(outpk + (size_t)node * HD + lane * 2) = make_uint2(split_pack(ax), split_pack(ay));
}

// ---------------- split-fp16 MFMA GEMM ----------------
// A: packed [M][K]; Bt: packed [N][K] (pre-transposed).
// MODE 0: Yout[m][n] = A@B                       (fp32 out, no activation)
// MODE 1: Hout[m][n] = pack(relu(A@B + bias))    (packed split out)
// MODE 2: score[m]  += sum_n relu(A@B+bias)[m][n] * m3[n]   (atomic)
template<int MODE>
__launch_bounds__(256, 2)
__global__ void k_mfma_gemm(const u32* __restrict__ Apk, const u32* __restrict__ Btpk,
                            const float* __restrict__ bias, float* __restrict__ Yout,
                            u32* __restrict__ Hout, const float* __restrict__ m3,
                            float* __restrict__ score, int M, int K, int N){
  __shared__ unsigned short As_h[128 * 40], As_l[128 * 40];
  __shared__ unsigned short Bs_h[128 * 40], Bs_l[128 * 40];
  const int tid = threadIdx.x;
  const int lane = tid & 63, wid = tid >> 6;
  const int lm = lane & 15, lg = lane >> 4;
  const int mq = (wid & 1) * 64, nq = (wid >> 1) * 64;
  const int m0 = blockIdx.x * 128, n0 = blockIdx.y * 128;

  floatx4 accA[4][4], accB[4][4];
  #pragma unroll
  for(int i = 0; i < 4; i++)
    #pragma unroll
    for(int j = 0; j < 4; j++){
      accA[i][j] = (floatx4){0.f, 0.f, 0.f, 0.f};
      accB[i][j] = (floatx4){0.f, 0.f, 0.f, 0.f};
    }

  for(int k0 = 0; k0 < K; k0 += 32){
    uint4 av[4], bv[4];
    #pragma unroll
    for(int j = 0; j < 4; j++){
      int li = tid + j * 256;
      int row = li >> 3, kc = (li & 7) * 4;
      int ar = m0 + row; if(ar >= M) ar = M - 1;
      av[j] = *(const uint4*)(Apk + (size_t)ar * K + k0 + kc);
      bv[j] = *(const uint4*)(Btpk + (size_t)(n0 + row) * K + k0 + kc);
    }
    __syncthreads();
    #pragma unroll
    for(int j = 0; j < 4; j++){
      int li = tid + j * 256;
      int row = li >> 3, kc = (li & 7) * 4;
      int base = row * 40 + kc;
      ushort4 h, l;
      h.x = (unsigned short)(av[j].x & 0xffff); l.x = (unsigned short)(av[j].x >> 16);
      h.y = (unsigned short)(av[j].y & 0xffff); l.y = (unsigned short)(av[j].y >> 16);
      h.z = (unsigned short)(av[j].z & 0xffff); l.z = (unsigned short)(av[j].z >> 16);
      h.w = (unsigned short)(av[j].w & 0xffff); l.w = (unsigned short)(av[j].w >> 16);
      *(ushort4*)&As_h[base] = h;
      *(ushort4*)&As_l[base] = l;
      h.x = (unsigned short)(bv[j].x & 0xffff); l.x = (unsigned short)(bv[j].x >> 16);
      h.y = (unsigned short)(bv[j].y & 0xffff); l.y = (unsigned short)(bv[j].y >> 16);
      h.z = (unsigned short)(bv[j].z & 0xffff); l.z = (unsigned short)(bv[j].z >> 16);
      h.w = (unsigned short)(bv[j].w & 0xffff); l.w = (unsigned short)(bv[j].w >> 16);
      *(ushort4*)&Bs_h[base] = h;
      *(ushort4*)&Bs_l[base] = l;
    }
    __syncthreads();

    half8 fa_h[4], fa_l[4], fb_h[4], fb_l[4];
    #pragma unroll
    for(int s = 0; s < 4; s++){
      int ra = (mq + s * 16 + lm) * 40 + lg * 8;
      fa_h[s] = *(const half8*)&As_h[ra];
      fa_l[s] = *(const half8*)&As_l[ra];
      int rb = (nq + s * 16 + lm) * 40 + lg * 8;
      fb_h[s] = *(const half8*)&Bs_h[rb];
      fb_l[s] = *(const half8*)&Bs_l[rb];
    }
    #pragma unroll
    for(int i = 0; i < 4; i++)
      #pragma unroll
      for(int j = 0; j < 4; j++){
        accA[i][j] = __builtin_amdgcn_mfma_f32_16x16x32_f16(fa_h[i], fb_h[j], accA[i][j], 0, 0, 0);
        accB[i][j] = __builtin_amdgcn_mfma_f32_16x16x32_f16(fa_h[i], fb_l[j], accB[i][j], 0, 0, 0);
        accB[i][j] = __builtin_amdgcn_mfma_f32_16x16x32_f16(fa_l[i], fb_h[j], accB[i][j], 0, 0, 0);
      }
  }

  const float inv4096 = 1.f / 4096.f;
  if(MODE == 0){
    #pragma unroll
    for(int i = 0; i < 4; i++)
      #pragma unroll
      for(int r = 0; r < 4; r++){
        int m = m0 + mq + i * 16 + lg * 4 + r;
        if(m < M){
          #pragma unroll
          for(int j = 0; j < 4; j++){
            int c = n0 + nq + j * 16 + lm;
            Yout[(size_t)m * N + c] = accA[i][j][r] + accB[i][j][r] * inv4096;
          }
        }
      }
  } else if(MODE == 1){
    #pragma unroll
    for(int i = 0; i < 4; i++)
      #pragma unroll
      for(int r = 0; r < 4; r++){
        int m = m0 + mq + i * 16 + lg * 4 + r;
        if(m < M){
          #pragma unroll
          for(int j = 0; j < 4; j++){
            int c = n0 + nq + j * 16 + lm;
            float v = fmaxf(accA[i][j][r] + accB[i][j][r] * inv4096 + bias[c], 0.f);
            Hout[(size_t)m * N + c] = split_pack(v);
          }
        }
      }
  } else {
    #pragma unroll
    for(int i = 0; i < 4; i++)
      #pragma unroll
      for(int r = 0; r < 4; r++){
        float s = 0.f;
        #pragma unroll
        for(int j = 0; j < 4; j++){
          int c = n0 + nq + j * 16 + lm;
          float v = fmaxf(accA[i][j][r] + accB[i][j][r] * inv4096 + bias[c], 0.f);
          s = fmaf(v, m3[c], s);
        }
        s += __shfl_xor(s, 1, 64);
        s += __shfl_xor(s, 2, 64);
        s += __shfl_xor(s, 4, 64);
        s += __shfl_xor(s, 8, 64);
        int m = m0 + mq + i * 16 + lg * 4 + r;
        if(lm == 0 && m < M) atomicAdd(&score[m], s);
      }
  }
}

__global__ void k_final(const float* __restrict__ s1, const float* __restrict__ s2,
                        const float* __restrict__ b3, float* __restrict__ out){
  int i = blockIdx.x * 256 + threadIdx.x;
  if(i < NN){
    float b = 9.f * b3[0];
    out[i] = (s1[i] + b) * (s2[i] + b);
  }
}

// ---------------- launcher ----------------
extern "C" void kernel_launch(void* const* d_in, const int* in_sizes, int n_in,
                              void* d_out, int out_size, void* d_ws, size_t ws_size,
                              hipStream_t stream){
  const int*   a1r = (const int*)d_in[0];
  const int*   a1c = (const int*)d_in[1];
  const float* a1v = (const float*)d_in[2];
  const int*   a2r = (const int*)d_in[3];
  const int*   a2c = (const int*)d_in[4];
  const float* a2v = (const float*)d_in[5];
  const float* w1  = (const float*)d_in[6];
  const float* w[8];
  for(int i = 0; i < 8; i++) w[i] = (const float*)d_in[7 + i];
  const float* m1 = (const float*)d_in[15];
  const float* b1 = (const float*)d_in[16];
  const float* m2 = (const float*)d_in[17];
  const float* b2 = (const float*)d_in[18];
  const float* m3 = (const float*)d_in[19];
  const float* b3 = (const float*)d_in[20];
  float* out = (float*)d_out;

  char* base = (char*)d_ws;
  size_t off = 0;
  auto alloc = [&](size_t bytes) -> char* {
    char* r = base + off;
    off += (bytes + 255) & ~(size_t)255;
    return r;
  };
  int*   c1ptr = (int*)  alloc((size_t)(NN + 1) * 4);
  int*   c1col = (int*)  alloc((size_t)NE * 4);
  float* c1val = (float*)alloc((size_t)NE * 4);
  int*   c2ptr = (int*)  alloc((size_t)(NN + 1) * 4);
  int*   c2col = (int*)  alloc((size_t)NE * 4);
  float* c2val = (float*)alloc((size_t)NE * 4);
  int*   cursor= (int*)  alloc((size_t)NN * 4);
  int*   sums  = (int*)  alloc(512);
  u32*   xpk   = (u32*)  alloc((size_t)NN * HD * 4);     // packed split x
  u32*   h1pk  = (u32*)  alloc((size_t)NN * HD2 * 4);    // packed split h1; y aliases front half
  float* sc1   = (float*)alloc((size_t)NN * 4);
  float* sc2   = (float*)alloc((size_t)NN * 4);
  u32*   wtpk[8];
  for(int i = 0; i < 8; i++) wtpk[i] = (u32*)alloc((size_t)HD * HD * 4);
  u32*   m1tpk = (u32*)alloc((size_t)HD2 * HD * 4);
  u32*   m2tpk = (u32*)alloc((size_t)HD2 * HD2 * 4);
  float* y = (float*)h1pk;   // [NN][128] fp32; dead before h1pk is written

  const int SCAN_BLOCKS = cdiv(NN, 1024);
  auto build_csr = [&](const int* rows, const int* cols, const float* vals,
                       int* rptr, int* rcol, float* rval){
    hipLaunchKernelGGL(k_zero_int, dim3(cdiv(NN, 256)), dim3(256), 0, stream, cursor, NN);
    hipLaunchKernelGGL(k_hist,     dim3(cdiv(NE, 256)), dim3(256), 0, stream, rows, cursor);
    hipLaunchKernelGGL(k_scan1,    dim3(SCAN_BLOCKS),   dim3(256), 0, stream, cursor, rptr, sums, NN);
    hipLaunchKernelGGL(k_scan2,    dim3(1),             dim3(128), 0, stream, sums, SCAN_BLOCKS);
    hipLaunchKernelGGL(k_scan3,    dim3(SCAN_BLOCKS),   dim3(256), 0, stream, rptr, cursor, sums, NN);
    hipLaunchKernelGGL(k_scatter,  dim3(cdiv(NE, 256)), dim3(256), 0, stream, rows, cols, vals, cursor, rcol, rval);
  };

  // pre-split + transpose all dense weights (packed h|l<<16, [N][K])
  auto splitw = [&](const float* W, u32* o, int K, int N){
    int total = K * N;
    hipLaunchKernelGGL(k_splitw, dim3(cdiv(total, 256)), dim3(256), 0, stream, W, o, K, N, total);
  };
  for(int i = 0; i < 8; i++) splitw(w[i], wtpk[i], HD, HD);
  splitw(m1, m1tpk, HD, HD2);
  splitw(m2, m2tpk, HD2, HD2);

  const int GX = cdiv(NN, 128);   // 782
  auto mlp = [&](float* score){
    hipLaunchKernelGGL((k_mfma_gemm<1>), dim3(GX, 2), dim3(256), 0, stream,
                       xpk, m1tpk, b1, (float*)nullptr, h1pk,
                       (const float*)nullptr, (float*)nullptr, NN, HD, HD2);
    hipLaunchKernelGGL((k_mfma_gemm<2>), dim3(GX, 2), dim3(256), 0, stream,
                       h1pk, m2tpk, b2, (float*)nullptr, (u32*)nullptr,
                       m3, score, NN, HD2, HD2);
  };

  auto branch = [&](const int* rptr, const int* rcol, const float* rval, float* score){
    hipLaunchKernelGGL((k_spmm<true>), dim3(cdiv(NN, 4)), dim3(256), 0, stream,
                       rptr, rcol, rval, w1, xpk);
    mlp(score);
    for(int i = 0; i < 8; i++){
      hipLaunchKernelGGL((k_mfma_gemm<0>), dim3(GX, 1), dim3(256), 0, stream,
                         xpk, wtpk[i], (const float*)nullptr, y, (u32*)nullptr,
                         (const float*)nullptr, (float*)nullptr, NN, HD, HD);
      if(i < 7)
        hipLaunchKernelGGL((k_spmm<true>),  dim3(cdiv(NN, 4)), dim3(256), 0, stream,
                           rptr, rcol, rval, y, xpk);
      else
        hipLaunchKernelGGL((k_spmm<false>), dim3(cdiv(NN, 4)), dim3(256), 0, stream,
                           rptr, rcol, rval, y, xpk);
      mlp(score);
    }
  };

  build_csr(a1r, a1c, a1v, c1ptr, c1col, c1val);
  build_csr(a2r, a2c, a2v, c2ptr, c2col, c2val);
  hipLaunchKernelGGL(k_zero_f2, dim3(cdiv(NN, 256)), dim3(256), 0, stream, sc1, sc2, NN);
  branch(c1ptr, c1col, c1val, sc1);
  branch(c2ptr, c2col, c2val, sc2);
  hipLaunchKernelGGL(k_final, dim3(cdiv(NN, 256)), dim3(256), 0, stream, sc1, sc2, b3, out);
}